// Round 7
// baseline (58.694 us; speedup 1.0000x reference)
//
#include <hip/hip_runtime.h>

// SpikeFP32LookupExp2: out[pos, :] = table_bits[j(pos), :] where
// j(pos) = sum_k (idx_bits[pos,k] > 0.5) << k.  Pure row-gather, memory-bound
// (~310 MB irreducible, 87% write; ceilings: copy 6.29 TB/s, fill 7.0 TB/s).
//
// Round 7: PHASE-SPLIT the read and write streams to cut HBM bus turnarounds.
//  Phase 1: each thread resolves j for all 16 of its positions (16 clustered
//           coalesced idx reads + ballots), j's held in registers
//           (j[16] fully unrolled -> static indexing, no scratch).
//  Phase 2: 16 back-to-back {L1 table gather -> 16 B nt store} iterations --
//           a near-pure write stream (writes are 1 KB contiguous per wave).
//  Everything else identical to the proven 51.6 us R3/R5 structure:
//  8 lanes/position, branchless ballot-j, nt stores, grid 4096 x 256.

typedef float floatx4 __attribute__((ext_vector_type(4)));

#define ITERS 16

__global__ __launch_bounds__(256) void spike_lookup_kernel(
    const float* __restrict__ idx_bits,   // [n_pos * 5]
    const float* __restrict__ table_bits, // [32 * 32]
    float* __restrict__ out,              // [n_pos * 32]
    long n_pos) {
  const long total4 = n_pos * 8;  // total float4 outputs
  const long nthreads = (long)gridDim.x * blockDim.x;
  const long gid = (long)blockIdx.x * blockDim.x + threadIdx.x;
  const int lane8 = (int)(gid & 7);              // which float4 of the row
  const int bit_lane = lane8 < 5 ? lane8 : 4;    // clamped: branchless load
  const unsigned shift = threadIdx.x & 56;       // group base within the wave

  unsigned j[ITERS];  // static-indexed (full unroll) -> stays in VGPRs

  // ---- Phase 1: clustered reads -> 16 ballot-resolved table indices ----
#pragma unroll
  for (int k = 0; k < ITERS; ++k) {
    long g = gid + (long)k * nthreads;
    long pos = g >> 3;
    if (pos >= n_pos) pos = n_pos - 1;           // safe clamp (exact shape: never taken)
    const float v = idx_bits[pos * 5 + bit_lane];
    const unsigned long long m = __ballot(v > 0.5f);
    j[k] = (unsigned)((m >> shift) & 31ull);     // group bits 5-7 discarded
  }

  // ---- Phase 2: near-pure write stream (gathers hit L1's 4 KB table) ----
#pragma unroll
  for (int k = 0; k < ITERS; ++k) {
    const long g = gid + (long)k * nthreads;
    if (g < total4) {
      const floatx4 row = *reinterpret_cast<const floatx4*>(
          table_bits + (j[k] << 5) + (lane8 << 2));
      __builtin_nontemporal_store(row,
                                  reinterpret_cast<floatx4*>(out + (g << 2)));
    }
  }
}

extern "C" void kernel_launch(void* const* d_in, const int* in_sizes, int n_in,
                              void* d_out, int out_size, void* d_ws, size_t ws_size,
                              hipStream_t stream) {
  const float* idx_bits = (const float*)d_in[0];    // (1024, 2048, 5) f32
  const float* table_bits = (const float*)d_in[1];  // (32, 32) f32
  float* out = (float*)d_out;                       // (1024, 2048, 32) f32

  const long n_pos = in_sizes[0] / 5;  // 2,097,152
  const long total4 = n_pos * 8;       // 16,777,216 float4 outputs
  const int block = 256;
  const int grid = (int)((total4 + (long)block * ITERS - 1) / ((long)block * ITERS));  // 4096

  spike_lookup_kernel<<<grid, block, 0, stream>>>(idx_bits, table_bits, out,
                                                  n_pos);
}